// Round 12
// baseline (217.390 us; speedup 1.0000x reference)
//
#include <hip/hip_runtime.h>
#include <math.h>

#define J 25
#define NJC 75             // J * CIN
#define NWAVE 4            // waves per block
#define NTHREADS 256
#define NFPW 4             // frames per wave
#define SCRW 2112          // per-wave scratch: 8 blocks x 264 bf16 (4224 B)

// const-image layout (bf16 element offsets in ws)
#define O_A1T  0           // B-frag [k=j][n=i], 1024
#define O_APP  1024        // frag [i'][j] (serves as B [k=j][n=i']), 1024
#define O_A4B  2048        // A-frag [m=i''][k=j], 1024
#define O_W2T  3072        // frag [l][d] (serves as B [k=d][n=l]), 2048
#define O_W3T  5120        // A-frag [m=d][k=l], 2 M-tiles, 2048
#define O_W1T  7168        // padded [tt][half][m][c8], half1=0, 1024
#define O_W4C  8192        // [n=c][k=d], 256
#define O_BPPB 8448        // 64 bf16 packed in C-reg order per (tt,half)
#define O_B4   8512        // 4 floats
#define XF_OFF 32768       // byte offset of xfrag region in ws

using bf16x4 = __attribute__((ext_vector_type(4))) __bf16;
using bf16x8 = __attribute__((ext_vector_type(8))) __bf16;
using f32x16 = __attribute__((ext_vector_type(16))) float;

__device__ inline bf16x8 zero8() {
    bf16x8 z;
    #pragma unroll
    for (int j = 0; j < 8; j++) z[j] = (__bf16)0.f;
    return z;
}

// ---------------------------------------------------------------------------
// Precompute (1 block): softmax(A1..A4), App=A3s@A2s, bpp=W3^T b2+b3, then
// emit the complete bf16 frag-layout constant image to ws.
// ---------------------------------------------------------------------------
__global__ void gcn_precompute(
    const float* __restrict__ A1, const float* __restrict__ W1, const float* __restrict__ b1,
    const float* __restrict__ A2, const float* __restrict__ W2, const float* __restrict__ b2,
    const float* __restrict__ A3, const float* __restrict__ W3, const float* __restrict__ b3,
    const float* __restrict__ A4, const float* __restrict__ W4, const float* __restrict__ b4,
    __bf16* __restrict__ cw)
{
    __shared__ float T[3125];      // T0..T3 softmax(A1..A4), T4 = App
    __shared__ float bpp[64];
    float* T0 = T;        float* T1 = T + 625;  float* T2 = T + 1250;
    float* T3 = T + 1875; float* T4 = T + 2500;
    const int t = threadIdx.x;

    if (t < 100) {
        const int m = t / J, i = t % J;
        const float* Asrc = (m == 0) ? A1 : (m == 1) ? A2 : (m == 2) ? A3 : A4;
        float row[J];
        float mx = -1e30f;
        #pragma unroll
        for (int j = 0; j < J; j++) { row[j] = Asrc[i * J + j]; mx = fmaxf(mx, row[j]); }
        float s = 0.f;
        #pragma unroll
        for (int j = 0; j < J; j++) { row[j] = __expf(row[j] - mx); s += row[j]; }
        const float inv = 1.f / s;
        float* dst = T + m * 625 + i * J;
        #pragma unroll
        for (int j = 0; j < J; j++) dst[j] = row[j] * inv;
    }
    if (t < 64) {                                      // bpp = W3^T b2 + b3
        float s = b3[t];
        #pragma unroll
        for (int l = 0; l < 32; l++) s += W3[l * 64 + t] * b2[l];
        bpp[t] = s;
    }
    __syncthreads();

    for (int idx = t; idx < 625; idx += 256) {        // App = A3s @ A2s
        const int i = idx / J, jj = idx % J;
        float s = 0.f;
        #pragma unroll
        for (int k = 0; k < J; k++) s += T2[i * J + k] * T1[k * J + jj];
        T4[idx] = s;
    }
    __syncthreads();

    // ---- frag-layout tables (mappings R4..R8-verified) ----
    for (int i = t; i < 1024; i += 256) {
        const int b = i >> 8, n = (i >> 3) & 31, jj = i & 7, j = 8 * b + jj;
        const bool ok = (j < J) && (n < J);
        cw[O_A1T + i] = (__bf16)(ok ? T0[n * J + j] : 0.f);
        cw[O_APP + i] = (__bf16)(ok ? T4[n * J + j] : 0.f);
        cw[O_A4B + i] = (__bf16)(ok ? T3[n * J + j] : 0.f);
    }
    for (int i = t; i < 2048; i += 256) {
        const int b = i >> 8, m = (i >> 3) & 31, jj = i & 7;
        cw[O_W2T + i] = (__bf16)W2[(8 * b + jj) * 32 + m];             // [l][d]
        const int tt = i >> 10, r = i & 1023;
        const int b3i = r >> 8, m3 = (r >> 3) & 31, j3 = r & 7;
        cw[O_W3T + i] = (__bf16)W3[(8 * b3i + j3) * 64 + tt * 32 + m3]; // [m=d][k=l]
    }
    for (int i = t; i < 1024; i += 256) {             // W1T padded, half1 = 0
        const int tt = i >> 9, r = i & 511, hf = r >> 8, q = r & 255;
        const int m = q >> 3, c = q & 7, d = tt * 32 + m;
        float v = 0.f;
        if (hf == 0) {
            if (c < 3) v = W1[c * 64 + d];
            else if (c == 3) v = b1[d];
        }
        cw[O_W1T + i] = (__bf16)v;
    }
    if (t < 256)
        cw[O_W4C + t] = (t < 192) ? (__bf16)W4[(t & 63) * 3 + (t >> 6)] : (__bf16)0.f;

    if (t < 64) {                                      // packed bias, C-reg order
        const int tt = t >> 5, rem = t & 31, hf = rem >> 4, q = rem & 15;
        const int g = q >> 2, r2 = q & 3;
        cw[O_BPPB + t] = (__bf16)bpp[tt * 32 + 8 * g + 4 * hf + r2];
    }
    float* fb4 = (float*)(cw + O_B4);
    if (t >= 64 && t < 68) fb4[t - 64] = (t < 67) ? b4[t - 64] : 0.f;
}

// ---------------------------------------------------------------------------
// X pre-transform: xfrag[f][m(4)][k(32)] bf16, 128 el (256 B) per frame.
//   m<3 : xfrag = x[f][j=k][c=m] for k<25, else 0   (K-pad zeros baked in)
//   m=3 : ones row (bias slot), 1 for k<25 else 0
// One thread per 8 consecutive bf16 -> one dwordx4 store (fully coalesced).
// ---------------------------------------------------------------------------
__global__ void gcn_xprep(const float* __restrict__ x,
                          __bf16* __restrict__ xf, const int total8)
{
    int idx = blockIdx.x * blockDim.x + threadIdx.x;
    if (idx >= total8) return;
    const int f = idx >> 4, r = idx & 15;       // r = m*4 + b
    const int m = r >> 2, b = r & 3;
    bf16x8 v;
    #pragma unroll
    for (int jj = 0; jj < 8; jj++) {
        const int k = 8 * b + jj;
        float val = 0.f;
        if (k < J) val = (m < 3) ? x[(long)f * NJC + k * 3 + m] : 1.f;
        v[jj] = (__bf16)val;
    }
    *(bf16x8*)&xf[(long)idx * 8] = v;
}

// ---------------------------------------------------------------------------
// Fused kernel (R8 structure; X from pre-formatted global frags when xf!=0).
// One frame per wave-iteration; weights register-resident; per-wave LDS ops
// in-order -> zero barriers. Scratch: 8 blocks x 264 bf16 per wave.
//
// mfma_f32_32x32x16_bf16 (verified): A[m][k]: m=lane&31, k=8*(lane>>5)+j+16ks
//   B[k][n]: n=lane&31, same k.  C/D: col=lane&31, row=(reg&3)+8*(reg>>2)+4*(lane>>5)
//
// Scratch schedule: (fallback only: X A-frag rows 0-3, blks 0-3) -> P2 H
// (blks 0-7) -> P3 U (blks 0-3) -> P4 V^T (blks 4-7) -> P5 HD (blks 0-7)
// -> P6 P (blks 0-3).  K-pads need no zeroing (B-side tables have zero rows
// for k>=25; junk is finite, 0*junk=0).  Ones-row is DATA (R10 lesson) —
// in xf mode it is baked into xfrag; in fallback it is rewritten per frame.
// ---------------------------------------------------------------------------
__global__ __launch_bounds__(NTHREADS, 4) void gcn_fused(
    const float* __restrict__ x,
    const __bf16* __restrict__ cw,
    const __bf16* __restrict__ xf,      // may be null -> LDS scatter fallback
    float* __restrict__ out)
{
    __shared__ __align__(16) __bf16 SCR[NWAVE * SCRW];

    const int t = threadIdx.x;
    const int w = t >> 6, lane = t & 63, ln = lane & 31, half = lane >> 5;
    const int fo = ln * 8;
    __bf16* sc = &SCR[w * SCRW];

    const long fbase = ((long)blockIdx.x * NWAVE + w) * NFPW;

    // ---- first-frame X prefetch (either mode)
    bf16x8 xr0, xr1;
    float xv0 = 0.f, xv1 = 0.f;
    if (xf) {
        const __bf16* xp = xf + fbase * 128 + (ln & 3) * 32;
        xr0 = *(const bf16x8*)(xp + 8 * half);
        xr1 = *(const bf16x8*)(xp + 16 + 8 * half);
    } else {
        const long xb = fbase * NJC;
        xv0 = x[xb + lane];
        xv1 = (lane < NJC - 64) ? x[xb + 64 + lane] : 0.f;
    }

    // ---- register frag loads (once per wave, from global ws image)
    bf16x8 rA1T[2], rApp[2], rA4b[2], rW1[2], rW2[4], rW3[4], rW4[4], rBpp[4];
    #pragma unroll
    for (int ks = 0; ks < 2; ks++) {
        rA1T[ks] = *(const bf16x8*)&cw[O_A1T + (2 * ks + half) * 256 + fo];
        rApp[ks] = *(const bf16x8*)&cw[O_APP + (2 * ks + half) * 256 + fo];
        rA4b[ks] = *(const bf16x8*)&cw[O_A4B + (2 * ks + half) * 256 + fo];
        rW1[ks]  = *(const bf16x8*)&cw[O_W1T + ks * 512 + half * 256 + fo];
    }
    #pragma unroll
    for (int ks = 0; ks < 4; ks++)
        rW2[ks] = *(const bf16x8*)&cw[O_W2T + (half + 2 * ks) * 256 + fo];
    #pragma unroll
    for (int tt = 0; tt < 2; tt++)
        #pragma unroll
        for (int ks = 0; ks < 2; ks++)
            rW3[tt * 2 + ks] = *(const bf16x8*)&cw[O_W3T + tt * 1024 + (half + 2 * ks) * 256 + fo];
    #pragma unroll
    for (int ks = 0; ks < 4; ks++) {
        rW4[ks] = zero8();
        if (ln < 3) rW4[ks] = *(const bf16x8*)&cw[O_W4C + ln * 64 + (half + 2 * ks) * 8];
    }
    #pragma unroll
    for (int tt = 0; tt < 2; tt++)
        #pragma unroll
        for (int p = 0; p < 2; p++)
            rBpp[tt * 2 + p] = *(const bf16x8*)&cw[O_BPPB + (tt * 2 + half) * 16 + p * 8];
    float b4v = 0.f;
    if (ln < 3) b4v = ((const float*)(cw + O_B4))[ln];

    // ---- shared zero accumulator (MFMA allows D != C)
    f32x16 Z;
    #pragma unroll
    for (int z = 0; z < 16; z++) Z[z] = 0.f;

    // fallback scatter coords (frame-independent)
    const int c0 = lane % 3, j0 = lane / 3;
    const int sc0 = (j0 >> 3) * 264 + c0 * 8 + (j0 & 7);
    const int i1 = 64 + lane, c1 = i1 % 3, j1 = i1 / 3;
    const int sc1 = (j1 >> 3) * 264 + c1 * 8 + (j1 & 7);
    const int so = (ln >> 3) * 264 + 24 + (ln & 7);
    const __bf16 ov = (ln < J) ? (__bf16)1.f : (__bf16)0.f;

    for (int fi = 0; fi < NFPW; fi++) {
        const long f = fbase + fi;

        // ---- acquire P1 A-operands + prefetch next frame
        bf16x8 a1op0, a1op1;
        bf16x8 nxr0, nxr1;
        float nxv0 = 0.f, nxv1 = 0.f;
        if (xf) {
            a1op0 = xr0; a1op1 = xr1;
            if (fi + 1 < NFPW) {
                const __bf16* xp = xf + (f + 1) * 128 + (ln & 3) * 32;
                nxr0 = *(const bf16x8*)(xp + 8 * half);
                nxr1 = *(const bf16x8*)(xp + 16 + 8 * half);
            }
        } else {
            sc[sc0] = (__bf16)xv0;
            if (lane < NJC - 64) sc[sc1] = (__bf16)xv1;
            if (half == 0) sc[so] = ov;                 // rewritten EVERY frame
            if (fi + 1 < NFPW) {
                const long nxb = (f + 1) * NJC;
                nxv0 = x[nxb + lane];
                if (lane < NJC - 64) nxv1 = x[nxb + 64 + lane];
            }
            a1op0 = *(const bf16x8*)&sc[half * 264 + fo];
            a1op1 = *(const bf16x8*)&sc[(2 + half) * 264 + fo];
        }

        // ---- P1: Y^T = Xaug^T @ A1T  (M=c rows 0..3, N=i, K=j pad32)
        f32x16 accY = __builtin_amdgcn_mfma_f32_32x32x16_bf16(a1op0, rA1T[0], Z, 0, 0, 0);
        accY = __builtin_amdgcn_mfma_f32_32x32x16_bf16(a1op1, rA1T[1], accY, 0, 0, 0);

        // ---- P2: H^T = relu(W1 @ Y^T); Y consumed in-register
        bf16x8 yb;
        #pragma unroll
        for (int jj = 0; jj < 8; jj++)
            yb[jj] = (half == 0 && jj < 4) ? (__bf16)accY[jj] : (__bf16)0.f;
        #pragma unroll
        for (int tt = 0; tt < 2; tt++) {
            f32x16 acc = __builtin_amdgcn_mfma_f32_32x32x16_bf16(rW1[tt], yb, Z, 0, 0, 0);
            #pragma unroll
            for (int g = 0; g < 4; g++) {
                bf16x4 p;
                #pragma unroll
                for (int r2 = 0; r2 < 4; r2++) p[r2] = (__bf16)fmaxf(acc[4 * g + r2], 0.f);
                *(bf16x4*)&sc[(tt * 4 + g) * 264 + fo + 4 * half] = p;
            }
        }

        // ---- P3: U = H @ W2  (C cols = l, rows = i)
        f32x16 accU;
        {
            bf16x8 a0 = *(const bf16x8*)&sc[half * 264 + fo];
            accU = __builtin_amdgcn_mfma_f32_32x32x16_bf16(a0, rW2[0], Z, 0, 0, 0);
            #pragma unroll
            for (int ks = 1; ks < 4; ks++) {
                bf16x8 a = *(const bf16x8*)&sc[(half + 2 * ks) * 264 + fo];
                accU = __builtin_amdgcn_mfma_f32_32x32x16_bf16(a, rW2[ks], accU, 0, 0, 0);
            }
        }
        #pragma unroll
        for (int g = 0; g < 4; g++) {                   // U frag [k=i][n=l], blks 0-3
            bf16x4 p;
            #pragma unroll
            for (int r2 = 0; r2 < 4; r2++) p[r2] = (__bf16)accU[4 * g + r2];
            *(bf16x4*)&sc[g * 264 + fo + 4 * half] = p;
        }

        // ---- P4: V^T = U^T @ App^T  (C cols = i', rows = l)
        f32x16 accV;
        {
            bf16x8 a0 = *(const bf16x8*)&sc[half * 264 + fo];
            accV = __builtin_amdgcn_mfma_f32_32x32x16_bf16(a0, rApp[0], Z, 0, 0, 0);
            bf16x8 a1 = *(const bf16x8*)&sc[(2 + half) * 264 + fo];
            accV = __builtin_amdgcn_mfma_f32_32x32x16_bf16(a1, rApp[1], accV, 0, 0, 0);
        }
        #pragma unroll
        for (int g = 0; g < 4; g++) {                   // V^T frag [k=l][n=i'], blks 4-7
            bf16x4 p;
            #pragma unroll
            for (int r2 = 0; r2 < 4; r2++) p[r2] = (__bf16)accV[4 * g + r2];
            *(bf16x4*)&sc[(4 + g) * 264 + fo + 4 * half] = p;
        }

        // ---- P5: HD^T = relu(W3 @ V^T + bpp)  (C cols = i', rows = d)
        bf16x8 vb0 = *(const bf16x8*)&sc[(4 + half) * 264 + fo];
        bf16x8 vb1 = *(const bf16x8*)&sc[(6 + half) * 264 + fo];
        #pragma unroll
        for (int tt = 0; tt < 2; tt++) {
            f32x16 acc = __builtin_amdgcn_mfma_f32_32x32x16_bf16(rW3[tt * 2 + 0], vb0, Z, 0, 0, 0);
            acc = __builtin_amdgcn_mfma_f32_32x32x16_bf16(rW3[tt * 2 + 1], vb1, acc, 0, 0, 0);
            #pragma unroll
            for (int g = 0; g < 4; g++) {
                bf16x4 p;
                #pragma unroll
                for (int r2 = 0; r2 < 4; r2++) {
                    const int q = g * 4 + r2;
                    const float bias = (float)rBpp[tt * 2 + (q >> 3)][q & 7];
                    p[r2] = (__bf16)fmaxf(acc[4 * g + r2] + bias, 0.f);
                }
                *(bf16x4*)&sc[(tt * 4 + g) * 264 + fo + 4 * half] = p;
            }
        }

        // ---- P6: P = HD @ W4  (C cols = c, rows = i')
        f32x16 accP;
        {
            bf16x8 a0 = *(const bf16x8*)&sc[half * 264 + fo];
            accP = __builtin_amdgcn_mfma_f32_32x32x16_bf16(a0, rW4[0], Z, 0, 0, 0);
            #pragma unroll
            for (int ks = 1; ks < 4; ks++) {
                bf16x8 a = *(const bf16x8*)&sc[(half + 2 * ks) * 264 + fo];
                accP = __builtin_amdgcn_mfma_f32_32x32x16_bf16(a, rW4[ks], accP, 0, 0, 0);
            }
        }
        #pragma unroll
        for (int g = 0; g < 4; g++) {                   // P frag [k=i'][n=c], blks 0-3
            bf16x4 p;
            #pragma unroll
            for (int r2 = 0; r2 < 4; r2++) p[r2] = (__bf16)accP[4 * g + r2];
            *(bf16x4*)&sc[g * 264 + fo + 4 * half] = p;
        }

        // ---- P7: out = A4 @ P + b4, direct global stores
        f32x16 accO;
        {
            bf16x8 b0 = *(const bf16x8*)&sc[half * 264 + fo];
            accO = __builtin_amdgcn_mfma_f32_32x32x16_bf16(rA4b[0], b0, Z, 0, 0, 0);
            bf16x8 b1 = *(const bf16x8*)&sc[(2 + half) * 264 + fo];
            accO = __builtin_amdgcn_mfma_f32_32x32x16_bf16(rA4b[1], b1, accO, 0, 0, 0);
        }
        if (ln < 3) {
            const long ob = f * NJC;
            #pragma unroll
            for (int r = 0; r < 16; r++) {
                const int row = (r & 3) + 8 * (r >> 2) + 4 * half;
                if (row < J) out[ob + row * 3 + ln] = accO[r] + b4v;
            }
        }

        xr0 = nxr0; xr1 = nxr1; xv0 = nxv0; xv1 = nxv1;
    }
}

// ---------------------------------------------------------------------------
extern "C" void kernel_launch(void* const* d_in, const int* in_sizes, int n_in,
                              void* d_out, int out_size, void* d_ws, size_t ws_size,
                              hipStream_t stream)
{
    const float* x  = (const float*)d_in[0];
    const float* A1 = (const float*)d_in[1];
    const float* W1 = (const float*)d_in[2];
    const float* b1 = (const float*)d_in[3];
    const float* A2 = (const float*)d_in[4];
    const float* W2 = (const float*)d_in[5];
    const float* b2 = (const float*)d_in[6];
    const float* A3 = (const float*)d_in[7];
    const float* W3 = (const float*)d_in[8];
    const float* b3 = (const float*)d_in[9];
    const float* A4 = (const float*)d_in[10];
    const float* W4 = (const float*)d_in[11];
    const float* b4 = (const float*)d_in[12];
    float* out = (float*)d_out;
    __bf16* cw = (__bf16*)d_ws;

    const int NT = in_sizes[0] / NJC;                 // 65536
    const int nblocks = NT / (NWAVE * NFPW);          // 4096

    // xfrag fits? (256 B per frame after the 32 KB const region)
    const size_t need = (size_t)XF_OFF + (size_t)NT * 256;
    __bf16* xfp = (ws_size >= need) ? (__bf16*)((char*)d_ws + XF_OFF) : nullptr;

    gcn_precompute<<<1, 256, 0, stream>>>(
        A1, W1, b1, A2, W2, b2, A3, W3, b3, A4, W4, b4, cw);
    if (xfp) {
        const int total8 = NT * 16;                   // 8-bf16 groups
        gcn_xprep<<<(total8 + 255) / 256, 256, 0, stream>>>(x, xfp, total8);
    }
    gcn_fused<<<nblocks, NTHREADS, 0, stream>>>(x, cw, xfp, out);
}

// Round 13
// 146.804 us; speedup vs baseline: 1.4808x; 1.4808x over previous
//
#include <hip/hip_runtime.h>
#include <math.h>

#define J 25
#define NJC 75             // J * CIN
#define NWAVE 4            // waves per block
#define NTHREADS 256
#define NFPW 4             // frames per wave
#define SCRW 1056          // per-wave scratch: 4 blocks x 264 bf16 (X staging ONLY)

// const-image layout (bf16 element offsets in ws)
#define O_A1T  0           // B for P1, natural k=j, 1024
#define O_APP  1024        // B for P4, k32-permuted, 1024
#define O_A4B  2048        // A for P7, k32-permuted, 1024
#define O_W2T  3072        // B for P3, k64-permuted, 2048
#define O_W3T  5120        // A for P5, k32-permuted, 2 M-tiles, 2048
#define O_W1T  7168        // A for P2, padded [tt][half][m][c8], half1=0, 1024
#define O_W4C  8192        // B for P6, k64-permuted, [c][b][j], 256
#define O_BPPB 8448        // 64 bf16 packed in C-reg order per (tt,half)
#define O_B4   8512        // 4 floats

using bf16x8 = __attribute__((ext_vector_type(8))) __bf16;
using f32x16 = __attribute__((ext_vector_type(16))) float;

__device__ inline bf16x8 zero8() {
    bf16x8 z;
    #pragma unroll
    for (int j = 0; j < 8; j++) z[j] = (__bf16)0.f;
    return z;
}

// ---------------------------------------------------------------------------
// K-permutations (must match between table construction and producer packing):
//   C-ladder: rho(r,h) = (r&3) + 8*(r>>2) + 4*h   (C reg r of half h -> row)
//   K=32 operands: d32(s,h,j) = rho(8*s+j, h),                s in 0..1
//   K=64 operands: d64(s,h,j) = 32*(s>>1) + rho(8*(s&1)+j,h), s in 0..3
// Producer C -> operand: op[s][j] = acc[8*s+j] (K32) / acc_tile[s>>1][8*(s&1)+j] (K64)
// ---------------------------------------------------------------------------

// ---------------------------------------------------------------------------
// Precompute (1 block, 256 thr): softmax(A1..A4), App=A3s@A2s, bpp=W3^T b2+b3,
// then emit the bf16 frag tables with the K-permutations baked in.
// ---------------------------------------------------------------------------
__global__ void gcn_precompute(
    const float* __restrict__ A1, const float* __restrict__ W1, const float* __restrict__ b1,
    const float* __restrict__ A2, const float* __restrict__ W2, const float* __restrict__ b2,
    const float* __restrict__ A3, const float* __restrict__ W3, const float* __restrict__ b3,
    const float* __restrict__ A4, const float* __restrict__ W4, const float* __restrict__ b4,
    __bf16* __restrict__ cw)
{
    __shared__ float T[3125];      // T0..T3 softmax(A1..A4), T4 = App
    __shared__ float bpp[64];
    float* T0 = T;        float* T1 = T + 625;  float* T2 = T + 1250;
    float* T3 = T + 1875; float* T4 = T + 2500;
    const int t = threadIdx.x;

    if (t < 100) {
        const int m = t / J, i = t % J;
        const float* Asrc = (m == 0) ? A1 : (m == 1) ? A2 : (m == 2) ? A3 : A4;
        float row[J];
        float mx = -1e30f;
        #pragma unroll
        for (int j = 0; j < J; j++) { row[j] = Asrc[i * J + j]; mx = fmaxf(mx, row[j]); }
        float s = 0.f;
        #pragma unroll
        for (int j = 0; j < J; j++) { row[j] = __expf(row[j] - mx); s += row[j]; }
        const float inv = 1.f / s;
        float* dst = T + m * 625 + i * J;
        #pragma unroll
        for (int j = 0; j < J; j++) dst[j] = row[j] * inv;
    }
    if (t < 64) {                                      // bpp = W3^T b2 + b3
        float s = b3[t];
        #pragma unroll
        for (int l = 0; l < 32; l++) s += W3[l * 64 + t] * b2[l];
        bpp[t] = s;
    }
    __syncthreads();

    for (int idx = t; idx < 625; idx += 256) {        // App = A3s @ A2s
        const int i = idx / J, jj = idx % J;
        float s = 0.f;
        #pragma unroll
        for (int k = 0; k < J; k++) s += T2[i * J + k] * T1[k * J + jj];
        T4[idx] = s;
    }
    __syncthreads();

    // ---- A1T (natural k) | App, A4b (k32-permuted) ----
    for (int i = t; i < 1024; i += 256) {
        const int b = i >> 8, n = (i >> 3) & 31, jj = i & 7;
        const int kn = 8 * b + jj;                                  // natural
        cw[O_A1T + i] = (__bf16)((kn < J && n < J) ? T0[n * J + kn] : 0.f);
        const int s = b >> 1, h = b & 1, r = 8 * s + jj;            // s in 0..1
        const int k32 = (r & 3) + 8 * (r >> 2) + 4 * h;
        cw[O_APP + i] = (__bf16)((k32 < J && n < J) ? T4[n * J + k32] : 0.f);
        cw[O_A4B + i] = (__bf16)((k32 < J && n < J) ? T3[n * J + k32] : 0.f);
    }
    // ---- W2T (k64-perm) | W3T (k32-perm, 2 tiles) ----
    for (int i = t; i < 2048; i += 256) {
        {   // W2T: (b, n=l, j) = W2[d64][l]
            const int b = i >> 8, n = (i >> 3) & 31, jj = i & 7;
            const int s = b >> 1, h = b & 1, r = 8 * (s & 1) + jj;
            const int d = 32 * (s >> 1) + (r & 3) + 8 * (r >> 2) + 4 * h;
            cw[O_W2T + i] = (__bf16)W2[d * 32 + n];
        }
        {   // W3T: (tt, b, m, j) = W3[l=d32][tt*32+m]
            const int tt = i >> 10, rr = i & 1023;
            const int b = rr >> 8, m = (rr >> 3) & 31, jj = rr & 7;
            const int s = b >> 1, h = b & 1, r = 8 * s + jj;
            const int l = (r & 3) + 8 * (r >> 2) + 4 * h;
            cw[O_W3T + i] = (__bf16)W3[l * 64 + tt * 32 + m];
        }
    }
    // ---- W1T (unchanged: padded, half1=0, b1 in c=3) ----
    for (int i = t; i < 1024; i += 256) {
        const int tt = i >> 9, r = i & 511, hf = r >> 8, q = r & 255;
        const int m = q >> 3, c = q & 7, d = tt * 32 + m;
        float v = 0.f;
        if (hf == 0) {
            if (c < 3) v = W1[c * 64 + d];
            else if (c == 3) v = b1[d];
        }
        cw[O_W1T + i] = (__bf16)v;
    }
    // ---- W4c (k64-perm): [c][b][j] = W4[d64][c] ----
    if (t < 256) {
        const int c = t >> 6, b = (t >> 3) & 7, jj = t & 7;
        const int s = b >> 1, h = b & 1, r = 8 * (s & 1) + jj;
        const int d = 32 * (s >> 1) + (r & 3) + 8 * (r >> 2) + 4 * h;
        cw[O_W4C + t] = (c < 3) ? (__bf16)W4[d * 3 + c] : (__bf16)0.f;
    }
    // ---- packed bias in C-reg order per (tt,half) ----
    if (t < 64) {
        const int tt = t >> 5, rem = t & 31, hf = rem >> 4, q = rem & 15;
        cw[O_BPPB + t] = (__bf16)bpp[tt * 32 + (q & 3) + 8 * (q >> 2) + 4 * hf];
    }
    float* fb4 = (float*)(cw + O_B4);
    if (t >= 64 && t < 68) fb4[t - 64] = (t < 67) ? b4[t - 64] : 0.f;
}

// ---------------------------------------------------------------------------
// Fused kernel — fully register-direct pipeline. The K-permuted tables make
// every producer's C regs the next stage's operand verbatim: NO inter-stage
// LDS. LDS is used only to stage X (frame scatter -> A-frag); its ones-row
// and K-pad zeros are written ONCE (nothing overwrites blocks 0-3 anymore).
//
// mfma_f32_32x32x16_bf16 (verified): A[m][k]: m=lane&31, k=8*(lane>>5)+j+16ks
//   B[k][n]: n=lane&31, same k.  C/D: col(lane)=n, row(regs)=m ladder rho.
//
// Chain: P1 Y^T(Xaug@A1T) -> P2 H(W1@Y) -> P3 U(H@W2) -> P4 V(U@App^T)
//   -> P5 HD(W3@V^T+bpp) -> P6 P(HD@W4) -> P7 out(A4@P+b4); lane dims:
//   i -> i -> l... every hop lane-preserving, K from C rows via permutation.
// ---------------------------------------------------------------------------
__global__ __launch_bounds__(NTHREADS, 2) void gcn_fused(
    const float* __restrict__ x,
    const __bf16* __restrict__ cw,
    float* __restrict__ out)
{
    __shared__ __align__(16) __bf16 SCR[NWAVE * SCRW];

    const int t = threadIdx.x;
    const int w = t >> 6, lane = t & 63, ln = lane & 31, half = lane >> 5;
    const int fo = ln * 8;
    __bf16* sc = &SCR[w * SCRW];

    const long fbase = ((long)blockIdx.x * NWAVE + w) * NFPW;

    // ---- first-frame x prefetch
    long xb = fbase * NJC;
    float xv0 = x[xb + lane];
    float xv1 = (lane < NJC - 64) ? x[xb + 64 + lane] : 0.f;

    // ---- one-time X-region constants (blocks 0-3 are X-only now):
    //      ones row m=3 (bias slot) and K-pad zeros rows 0-2, k=25..31
    if (half == 0) sc[(ln >> 3) * 264 + 24 + (ln & 7)] = (ln < J) ? (__bf16)1.f : (__bf16)0.f;
    if (lane < 21) sc[3 * 264 + (lane / 7) * 8 + 1 + (lane % 7)] = (__bf16)0.f;

    // ---- register frag loads (once per wave, from L2-hot ws image)
    bf16x8 rA1T[2], rApp[2], rA4b[2], rW1[2], rW2[4], rW3[4], rW4[4], rBpp[4];
    #pragma unroll
    for (int ks = 0; ks < 2; ks++) {
        rA1T[ks] = *(const bf16x8*)&cw[O_A1T + (2 * ks + half) * 256 + fo];
        rApp[ks] = *(const bf16x8*)&cw[O_APP + (2 * ks + half) * 256 + fo];
        rA4b[ks] = *(const bf16x8*)&cw[O_A4B + (2 * ks + half) * 256 + fo];
        rW1[ks]  = *(const bf16x8*)&cw[O_W1T + ks * 512 + half * 256 + fo];
    }
    #pragma unroll
    for (int ks = 0; ks < 4; ks++)
        rW2[ks] = *(const bf16x8*)&cw[O_W2T + (half + 2 * ks) * 256 + fo];
    #pragma unroll
    for (int tt = 0; tt < 2; tt++)
        #pragma unroll
        for (int ks = 0; ks < 2; ks++)
            rW3[tt * 2 + ks] = *(const bf16x8*)&cw[O_W3T + tt * 1024 + (half + 2 * ks) * 256 + fo];
    #pragma unroll
    for (int ks = 0; ks < 4; ks++) {
        rW4[ks] = zero8();
        if (ln < 3) rW4[ks] = *(const bf16x8*)&cw[O_W4C + ln * 64 + (half + 2 * ks) * 8];
    }
    #pragma unroll
    for (int tt = 0; tt < 2; tt++)
        #pragma unroll
        for (int p = 0; p < 2; p++)
            rBpp[tt * 2 + p] = *(const bf16x8*)&cw[O_BPPB + (tt * 2 + half) * 16 + p * 8];
    float b4v = 0.f;
    if (ln < 3) b4v = ((const float*)(cw + O_B4))[ln];

    // ---- shared zero accumulator (MFMA allows D != C)
    f32x16 Z;
    #pragma unroll
    for (int z = 0; z < 16; z++) Z[z] = 0.f;

    // X scatter coords (frame-independent): element i -> A[c=i%3][k=i/3]
    const int c0 = lane % 3, j0 = lane / 3;
    const int sc0 = (j0 >> 3) * 264 + c0 * 8 + (j0 & 7);
    const int i1 = 64 + lane, c1 = i1 % 3, j1 = i1 / 3;
    const int sc1 = (j1 >> 3) * 264 + c1 * 8 + (j1 & 7);

    for (int fi = 0; fi < NFPW; fi++) {
        const long f = fbase + fi;

        // ---- X staging (only per-frame LDS writes)
        sc[sc0] = (__bf16)xv0;
        if (lane < NJC - 64) sc[sc1] = (__bf16)xv1;

        // ---- prefetch next frame's x
        float nxv0 = 0.f, nxv1 = 0.f;
        if (fi + 1 < NFPW) {
            const long nxb = (f + 1) * NJC;
            nxv0 = x[nxb + lane];
            if (lane < NJC - 64) nxv1 = x[nxb + 64 + lane];
        }

        // ---- P1: Y^T = Xaug^T @ A1T  (A from LDS, natural k)
        bf16x8 a0 = *(const bf16x8*)&sc[half * 264 + fo];
        bf16x8 a1 = *(const bf16x8*)&sc[(2 + half) * 264 + fo];
        f32x16 accY = __builtin_amdgcn_mfma_f32_32x32x16_bf16(a0, rA1T[0], Z, 0, 0, 0);
        accY = __builtin_amdgcn_mfma_f32_32x32x16_bf16(a1, rA1T[1], accY, 0, 0, 0);

        // ---- P2: H^T = relu(W1 @ Y^T); Y in-register; pack C -> K64 A-frag
        bf16x8 yb;
        #pragma unroll
        for (int jj = 0; jj < 8; jj++)
            yb[jj] = (half == 0 && jj < 4) ? (__bf16)accY[jj] : (__bf16)0.f;
        bf16x8 hf[4];
        #pragma unroll
        for (int tt = 0; tt < 2; tt++) {
            f32x16 acc = __builtin_amdgcn_mfma_f32_32x32x16_bf16(rW1[tt], yb, Z, 0, 0, 0);
            #pragma unroll
            for (int st = 0; st < 2; st++)
                #pragma unroll
                for (int jj = 0; jj < 8; jj++)
                    hf[2 * tt + st][jj] = (__bf16)fmaxf(acc[8 * st + jj], 0.f);
        }

        // ---- P3: U = H @ W2  (K=64, B table k64-permuted) -> C lane=l, rows=i
        f32x16 accU = __builtin_amdgcn_mfma_f32_32x32x16_bf16(hf[0], rW2[0], Z, 0, 0, 0);
        #pragma unroll
        for (int s = 1; s < 4; s++)
            accU = __builtin_amdgcn_mfma_f32_32x32x16_bf16(hf[s], rW2[s], accU, 0, 0, 0);
        bf16x8 uf[2];
        #pragma unroll
        for (int s = 0; s < 2; s++)
            #pragma unroll
            for (int jj = 0; jj < 8; jj++) uf[s][jj] = (__bf16)accU[8 * s + jj];

        // ---- P4: V = App @ U  (A=U^T regs, B table k32-permuted) -> lane=i', rows=l
        f32x16 accV = __builtin_amdgcn_mfma_f32_32x32x16_bf16(uf[0], rApp[0], Z, 0, 0, 0);
        accV = __builtin_amdgcn_mfma_f32_32x32x16_bf16(uf[1], rApp[1], accV, 0, 0, 0);
        bf16x8 vf[2];
        #pragma unroll
        for (int s = 0; s < 2; s++)
            #pragma unroll
            for (int jj = 0; jj < 8; jj++) vf[s][jj] = (__bf16)accV[8 * s + jj];

        // ---- P5: HD^T = relu(W3 @ V^T + bpp)  (A table k32-perm) -> lane=i', rows=d
        bf16x8 hd[4];
        #pragma unroll
        for (int tt = 0; tt < 2; tt++) {
            f32x16 acc = __builtin_amdgcn_mfma_f32_32x32x16_bf16(rW3[tt * 2 + 0], vf[0], Z, 0, 0, 0);
            acc = __builtin_amdgcn_mfma_f32_32x32x16_bf16(rW3[tt * 2 + 1], vf[1], acc, 0, 0, 0);
            #pragma unroll
            for (int st = 0; st < 2; st++)
                #pragma unroll
                for (int jj = 0; jj < 8; jj++) {
                    const float bias = (float)rBpp[2 * tt + st][jj];
                    hd[2 * tt + st][jj] = (__bf16)fmaxf(acc[8 * st + jj] + bias, 0.f);
                }
        }

        // ---- P6: P = HD @ W4  (K=64, B table k64-perm) -> C lane=c, rows=i'
        f32x16 accP = __builtin_amdgcn_mfma_f32_32x32x16_bf16(hd[0], rW4[0], Z, 0, 0, 0);
        #pragma unroll
        for (int s = 1; s < 4; s++)
            accP = __builtin_amdgcn_mfma_f32_32x32x16_bf16(hd[s], rW4[s], accP, 0, 0, 0);
        bf16x8 pf[2];
        #pragma unroll
        for (int s = 0; s < 2; s++)
            #pragma unroll
            for (int jj = 0; jj < 8; jj++) pf[s][jj] = (__bf16)accP[8 * s + jj];

        // ---- P7: out = A4 @ P + b4  (A table k32-perm) -> C lane=c, rows=i''
        f32x16 accO = __builtin_amdgcn_mfma_f32_32x32x16_bf16(rA4b[0], pf[0], Z, 0, 0, 0);
        accO = __builtin_amdgcn_mfma_f32_32x32x16_bf16(rA4b[1], pf[1], accO, 0, 0, 0);
        if (ln < 3) {
            const long ob = f * NJC;
            #pragma unroll
            for (int r = 0; r < 16; r++) {
                const int row = (r & 3) + 8 * (r >> 2) + 4 * half;
                if (row < J) out[ob + row * 3 + ln] = accO[r] + b4v;
            }
        }

        xv0 = nxv0; xv1 = nxv1;
    }
}

// ---------------------------------------------------------------------------
extern "C" void kernel_launch(void* const* d_in, const int* in_sizes, int n_in,
                              void* d_out, int out_size, void* d_ws, size_t ws_size,
                              hipStream_t stream)
{
    const float* x  = (const float*)d_in[0];
    const float* A1 = (const float*)d_in[1];
    const float* W1 = (const float*)d_in[2];
    const float* b1 = (const float*)d_in[3];
    const float* A2 = (const float*)d_in[4];
    const float* W2 = (const float*)d_in[5];
    const float* b2 = (const float*)d_in[6];
    const float* A3 = (const float*)d_in[7];
    const float* W3 = (const float*)d_in[8];
    const float* b3 = (const float*)d_in[9];
    const float* A4 = (const float*)d_in[10];
    const float* W4 = (const float*)d_in[11];
    const float* b4 = (const float*)d_in[12];
    float* out = (float*)d_out;
    __bf16* cw = (__bf16*)d_ws;

    const int NT = in_sizes[0] / NJC;                 // 65536
    const int nblocks = NT / (NWAVE * NFPW);          // 4096

    gcn_precompute<<<1, 256, 0, stream>>>(
        A1, W1, b1, A2, W2, b2, A3, W3, b3, A4, W4, b4, cw);
    gcn_fused<<<nblocks, NTHREADS, 0, stream>>>(x, cw, out);
}